// Round 1
// baseline (1454.836 us; speedup 1.0000x reference)
//
#include <hip/hip_runtime.h>

typedef __attribute__((ext_vector_type(8))) short bf16x8;
typedef __attribute__((ext_vector_type(4))) short s16x4;
typedef __attribute__((ext_vector_type(4))) float f32x4;

__device__ __forceinline__ short f2bf(float f) {
  union { float f; unsigned u; } v; v.f = f;
  unsigned r = v.u + 0x7fffu + ((v.u >> 16) & 1u);
  return (short)(r >> 16);
}

constexpr int MT = 64;      // rows per block tile
constexpr int ASTR = 72;    // A chunk stride (shorts): 64 + 8 pad
constexpr int HSTR = 264;   // H stride (shorts): 256 + 8 pad
constexpr int BSTR = 40;    // B chunk stride (shorts): 32 + 8 pad

struct SmemT {
  short As[MT * ASTR];      //  9216 B : layer-1 input k-chunk (gathered)
  short Hs[MT * HSTR];      // 33792 B : H1 then H2 (reused)
  short Bs[256 * BSTR];     // 20480 B : transposed weight k-chunk
  int   s_a[MT];
  int   s_b[MT];
  float s_inv[MT];
};                          // total 64256 B <= 64 KiB

// stage 32 k-rows of W[K][256] transposed into Bs[n][kk]
__device__ __forceinline__ void stage_B256(const float* __restrict__ W, int kc, int tid, short* Bs) {
  int n0 = (tid & 63) * 4;
  int kk0 = (tid >> 6) * 8;
  short tmp[4][8];
#pragma unroll
  for (int j = 0; j < 8; ++j) {
    const float4 v = *(const float4*)(W + (size_t)(kc + kk0 + j) * 256 + n0);
    tmp[0][j] = f2bf(v.x); tmp[1][j] = f2bf(v.y); tmp[2][j] = f2bf(v.z); tmp[3][j] = f2bf(v.w);
  }
#pragma unroll
  for (int i = 0; i < 4; ++i)
    *(bf16x8*)&Bs[(n0 + i) * BSTR + kk0] = *(bf16x8*)&tmp[i][0];
}

// stage 32 k-rows of W[K][128] transposed into Bs[n][kk]
__device__ __forceinline__ void stage_B128(const float* __restrict__ W, int kc, int tid, short* Bs) {
  int n0 = (tid & 31) * 4;
  int kk0 = (tid >> 5) * 4;
  short tmp[4][4];
#pragma unroll
  for (int j = 0; j < 4; ++j) {
    const float4 v = *(const float4*)(W + (size_t)(kc + kk0 + j) * 128 + n0);
    tmp[0][j] = f2bf(v.x); tmp[1][j] = f2bf(v.y); tmp[2][j] = f2bf(v.z); tmp[3][j] = f2bf(v.w);
  }
#pragma unroll
  for (int i = 0; i < 4; ++i)
    *(s16x4*)&Bs[(n0 + i) * BSTR + kk0] = *(s16x4*)&tmp[i][0];
}

// one 32-k MFMA step: A fragment from Abuf (rows wrow..wrow+15, cols acol..acol+31)
template <int NF>
__device__ __forceinline__ void mfma_step(const short* Abuf, int astride, int wrow, int acol,
                                          const short* Bs, int lane16, int kgrp, f32x4* acc) {
  bf16x8 a = *(const bf16x8*)&Abuf[(size_t)(wrow + lane16) * astride + acol + kgrp * 8];
#pragma unroll
  for (int f = 0; f < NF; ++f) {
    bf16x8 b = *(const bf16x8*)&Bs[(f * 16 + lane16) * BSTR + kgrp * 8];
    acc[f] = __builtin_amdgcn_mfma_f32_16x16x32_bf16(a, b, acc[f], 0, 0, 0);
  }
}

__global__ void count_kernel(const int* __restrict__ dst, float* __restrict__ cnt, int E) {
  int i = blockIdx.x * 256 + threadIdx.x;
  if (i < E) atomicAdd(&cnt[dst[i]], 1.0f);
}

template <bool IS_EDGE>
__launch_bounds__(256, 2)
__global__ void mlp_kernel(const float* __restrict__ node_emb, const float* __restrict__ edge_emb,
                           const int* __restrict__ src, const int* __restrict__ dst,
                           const float* __restrict__ W1, const float* __restrict__ b1,
                           const float* __restrict__ W2, const float* __restrict__ b2,
                           const float* __restrict__ W3, const float* __restrict__ b3,
                           const float* __restrict__ gam, const float* __restrict__ bet,
                           float* __restrict__ agg, const float* __restrict__ cnt,
                           float* __restrict__ out_base, int M) {
  __shared__ SmemT sm;
  const int tid = threadIdx.x;
  const int m0 = blockIdx.x * MT;
  const int wid = tid >> 6;
  const int lane = tid & 63;
  const int lane16 = lane & 15;
  const int kgrp = lane >> 4;
  const int wrow = wid * 16;

  if (IS_EDGE) {
    if (tid < MT) {
      int e = m0 + tid;
      sm.s_a[tid] = (e < M) ? src[e] : 0;
      sm.s_b[tid] = (e < M) ? dst[e] : 0;
    }
  } else {
    if (tid < MT) {
      int n = m0 + tid;
      sm.s_inv[tid] = (n < M) ? 1.0f / fmaxf(cnt[n], 1.0f) : 0.0f;
    }
  }
  __syncthreads();

  constexpr int K1 = IS_EDGE ? 384 : 256;
  f32x4 acc[16];
#pragma unroll
  for (int f = 0; f < 16; ++f) {
    f32x4 z = {0.f, 0.f, 0.f, 0.f};
    acc[f] = z;
  }

  // ---------------- layer 1: X(gathered) @ W1, K = K1, N = 256 ----------------
  for (int kb = 0; kb < K1; kb += 64) {
    __syncthreads();  // prior MFMA done reading As/Bs
    // gather-stage A chunk: 64 rows x 64 cols (fp32 -> bf16)
#pragma unroll
    for (int i = 0; i < 4; ++i) {
      int lin = i * 256 + tid;
      int row = lin >> 4;
      int c4 = (lin & 15) * 4;
      int gcol = kb + c4;
      float4 v = make_float4(0.f, 0.f, 0.f, 0.f);
      float scale = 1.0f;
      if (IS_EDGE) {
        const float* p;
        if (gcol < 128)       p = node_emb + (size_t)sm.s_a[row] * 128 + gcol;
        else if (gcol < 256)  p = node_emb + (size_t)sm.s_b[row] * 128 + (gcol - 128);
        else                  p = edge_emb + (size_t)(m0 + row) * 128 + (gcol - 256);
        v = *(const float4*)p;
      } else {
        int n = m0 + row;
        if (n < M) {
          if (gcol < 128) {
            v = *(const float4*)(node_emb + (size_t)n * 128 + gcol);
          } else {
            v = *(const float4*)(agg + (size_t)n * 128 + (gcol - 128));
            scale = sm.s_inv[row];
          }
        }
      }
      s16x4 o;
      o[0] = f2bf(v.x * scale); o[1] = f2bf(v.y * scale);
      o[2] = f2bf(v.z * scale); o[3] = f2bf(v.w * scale);
      *(s16x4*)&sm.As[row * ASTR + c4] = o;
    }
#pragma unroll
    for (int kc2 = 0; kc2 < 64; kc2 += 32) {
      __syncthreads();  // As visible / prior Bs reads done
      stage_B256(W1, kb + kc2, tid, sm.Bs);
      __syncthreads();  // Bs visible
      mfma_step<16>(sm.As, ASTR, wrow, kc2, sm.Bs, lane16, kgrp, acc);
    }
  }

  // H1 = relu(acc + b1) -> Hs  (Hs untouched so far; each wave writes own rows)
#pragma unroll
  for (int f = 0; f < 16; ++f) {
    int col = f * 16 + lane16;
    float bv = b1[col];
#pragma unroll
    for (int r = 0; r < 4; ++r) {
      float h = fmaxf(acc[f][r] + bv, 0.f);
      sm.Hs[(wrow + kgrp * 4 + r) * HSTR + col] = f2bf(h);
      acc[f][r] = 0.f;
    }
  }

  // ---------------- layer 2: H1 @ W2, K = 256, N = 256 ----------------
  for (int kc = 0; kc < 256; kc += 32) {
    __syncthreads();  // H1 writes visible (first iter) / prior Bs reads done
    stage_B256(W2, kc, tid, sm.Bs);
    __syncthreads();
    mfma_step<16>(sm.Hs, HSTR, wrow, kc, sm.Bs, lane16, kgrp, acc);
  }
  __syncthreads();  // all waves done reading Hs before overwrite

  // H2 = relu(acc + b2) -> Hs (overwrite)
#pragma unroll
  for (int f = 0; f < 16; ++f) {
    int col = f * 16 + lane16;
    float bv = b2[col];
#pragma unroll
    for (int r = 0; r < 4; ++r) {
      float h = fmaxf(acc[f][r] + bv, 0.f);
      sm.Hs[(wrow + kgrp * 4 + r) * HSTR + col] = f2bf(h);
      acc[f][r] = 0.f;
    }
  }

  // ---------------- layer 3: H2 @ W3, K = 256, N = 128 ----------------
  for (int kc = 0; kc < 256; kc += 32) {
    __syncthreads();  // H2 visible (first iter) / prior Bs reads done
    stage_B128(W3, kc, tid, sm.Bs);
    __syncthreads();
    mfma_step<8>(sm.Hs, HSTR, wrow, kc, sm.Bs, lane16, kgrp, acc);
  }

  // ---------------- epilogue: bias + LayerNorm + residual (+ agg atomics) ----------------
  float b3v[8], gv[8], bev[8];
#pragma unroll
  for (int f = 0; f < 8; ++f) {
    int col = f * 16 + lane16;
    b3v[f] = b3[col]; gv[f] = gam[col]; bev[f] = bet[col];
  }
#pragma unroll
  for (int r = 0; r < 4; ++r) {
    float o[8];
    float s1 = 0.f, s2 = 0.f;
#pragma unroll
    for (int f = 0; f < 8; ++f) {
      float x = acc[f][r] + b3v[f];
      o[f] = x; s1 += x; s2 += x * x;
    }
#pragma unroll
    for (int m = 1; m <= 8; m <<= 1) {
      s1 += __shfl_xor(s1, m);
      s2 += __shfl_xor(s2, m);
    }
    float mu = s1 * (1.f / 128.f);
    float var = s2 * (1.f / 128.f) - mu * mu;
    float rs = rsqrtf(var + 1e-5f);
    int row = wrow + kgrp * 4 + r;
    int rg = m0 + row;
    if (rg < M) {
      const float* resid = IS_EDGE ? (edge_emb + (size_t)rg * 128) : (node_emb + (size_t)rg * 128);
      float* op = out_base + (size_t)rg * 128;
      int d = IS_EDGE ? sm.s_b[row] : 0;
#pragma unroll
      for (int f = 0; f < 8; ++f) {
        int col = f * 16 + lane16;
        float y = (o[f] - mu) * rs * gv[f] + bev[f] + resid[col];
        op[col] = y;
        if (IS_EDGE) atomicAdd(&agg[(size_t)d * 128 + col], y);
      }
    }
  }
}

extern "C" void kernel_launch(void* const* d_in, const int* in_sizes, int n_in,
                              void* d_out, int out_size, void* d_ws, size_t ws_size,
                              hipStream_t stream) {
  const float* node_emb = (const float*)d_in[0];
  const float* edge_emb = (const float*)d_in[1];
  const int*   src      = (const int*)d_in[2];
  const int*   dst      = (const int*)d_in[3];
  const float* eW1 = (const float*)d_in[5];
  const float* eb1 = (const float*)d_in[6];
  const float* eW2 = (const float*)d_in[7];
  const float* eb2 = (const float*)d_in[8];
  const float* eW3 = (const float*)d_in[9];
  const float* eb3 = (const float*)d_in[10];
  const float* eg  = (const float*)d_in[11];
  const float* ebt = (const float*)d_in[12];
  const float* nW1 = (const float*)d_in[13];
  const float* nb1 = (const float*)d_in[14];
  const float* nW2 = (const float*)d_in[15];
  const float* nb2 = (const float*)d_in[16];
  const float* nW3 = (const float*)d_in[17];
  const float* nb3 = (const float*)d_in[18];
  const float* ng  = (const float*)d_in[19];
  const float* nbt = (const float*)d_in[20];

  const int Nn = in_sizes[0] / 128;
  const int Ee = in_sizes[2];

  float* agg = (float*)d_ws;                    // Nn*128 f32 sums
  float* cnt = agg + (size_t)Nn * 128;          // Nn f32 counts
  float* out_node = (float*)d_out;
  float* out_edge = out_node + (size_t)Nn * 128;

  hipMemsetAsync(d_ws, 0, ((size_t)Nn * 128 + Nn) * sizeof(float), stream);
  count_kernel<<<(Ee + 255) / 256, 256, 0, stream>>>(dst, cnt, Ee);
  mlp_kernel<true><<<(Ee + MT - 1) / MT, 256, 0, stream>>>(
      node_emb, edge_emb, src, dst, eW1, eb1, eW2, eb2, eW3, eb3, eg, ebt,
      agg, cnt, out_edge, Ee);
  mlp_kernel<false><<<(Nn + MT - 1) / MT, 256, 0, stream>>>(
      node_emb, edge_emb, src, dst, nW1, nb1, nW2, nb2, nW3, nb3, ng, nbt,
      agg, cnt, out_node, Nn);
}

// Round 2
// 1189.067 us; speedup vs baseline: 1.2235x; 1.2235x over previous
//
#include <hip/hip_runtime.h>

typedef __attribute__((ext_vector_type(8))) short bf16x8;
typedef __attribute__((ext_vector_type(4))) float f32x4;

__device__ __forceinline__ short f2bf(float f) {
  union { float f; unsigned u; } v; v.f = f;
  unsigned r = v.u + 0x7fffu + ((v.u >> 16) & 1u);
  return (short)(r >> 16);
}

__device__ __forceinline__ void gld_lds16(const short* g, short* l) {
  __builtin_amdgcn_global_load_lds((const __attribute__((address_space(1))) unsigned*)g,
                                   (__attribute__((address_space(3))) unsigned*)l,
                                   16, 0, 0);
}

// copy nSlots 16-byte slots of pre-formatted weights into LDS (async, linear)
__device__ __forceinline__ void stage(const short* __restrict__ g, short* l, int tid, int nSlots) {
#pragma unroll
  for (int s0 = 0; s0 < 4; ++s0) {
    int s = s0 * 256 + tid;
    if (s < nSlots) gld_lds16(g + (size_t)s * 8, l + (size_t)s * 8);
  }
}

// W[K][N] fp32  ->  bf16 fragments: slot s=( (kc*(N/16)+f)*64 + lane ), lane=(kg,l16)
// content: W[kc*32+kg*8+e][f*16+l16], e=0..7
__global__ void prep_kernel(const float* __restrict__ W, short* __restrict__ out, int K, int N) {
  int s = blockIdx.x * 256 + threadIdx.x;
  int NF = N >> 4;
  int total = (K >> 5) * NF * 64;
  if (s >= total) return;
  int l = s & 63, kcf = s >> 6;
  int kc = kcf / NF, f = kcf - kc * NF;
  int kg = l >> 4, l16 = l & 15;
  const float* p = W + (size_t)(kc * 32 + kg * 8) * N + f * 16 + l16;
  bf16x8 o;
#pragma unroll
  for (int e = 0; e < 8; ++e) o[e] = f2bf(p[(size_t)e * N]);
  *(bf16x8*)(out + (size_t)s * 8) = o;
}

__global__ void count_kernel(const int* __restrict__ dst, float* __restrict__ cnt, int E) {
  int i = blockIdx.x * 256 + threadIdx.x;
  if (i < E) atomicAdd(&cnt[dst[i]], 1.0f);
}

// H layout (block-shared, 64 rows x 256 cols bf16):
//   offset_shorts(row, col) = (col>>5)*2048 + row*32 + ((col>>3)&3)*8 + (col&7)
// -> A-frag read for chunk kc, rows rt*16+l16: 64 lanes hit 64 consecutive 16B slots.
template <bool IS_EDGE>
__launch_bounds__(256, 2)
__global__ void mlp_kernel(const float* __restrict__ node_emb, const float* __restrict__ edge_emb,
                           const int* __restrict__ src, const int* __restrict__ dst,
                           const short* __restrict__ w1p, const short* __restrict__ w2p,
                           const short* __restrict__ w3p,
                           const float* __restrict__ b1, const float* __restrict__ b2,
                           const float* __restrict__ b3,
                           const float* __restrict__ gam, const float* __restrict__ bet,
                           float* __restrict__ agg, const float* __restrict__ cnt,
                           float* __restrict__ out_base, int M) {
  __shared__ short Bs[2][8192];   // 2 x 16 KiB double-buffered weight chunk
  __shared__ short Hs[16384];     // 32 KiB activations (H1 then H2)

  const int tid = threadIdx.x;
  const int m0 = blockIdx.x * 64;
  const int w = tid >> 6;
  const int lane = tid & 63;
  const int l16 = lane & 15;
  const int kg = lane >> 4;

  // gather metadata parked in Hs until extracted
  int* s_a = (int*)Hs;
  int* s_b = s_a + 64;
  float* s_inv = (float*)(s_b + 64);

  if (tid < 64) {
    int rc = min(m0 + tid, M - 1);
    if (IS_EDGE) {
      s_a[tid] = src[rc];
      s_b[tid] = dst[rc];
    } else {
      s_inv[tid] = 1.0f / fmaxf(cnt[rc], 1.0f);
    }
  }
  stage(w1p, Bs[0], tid, 1024);
  __syncthreads();

  int gsr[4], gdr[4];
  float inv4[4];
#pragma unroll
  for (int rt = 0; rt < 4; ++rt) {
    int r = rt * 16 + l16;
    if (IS_EDGE) { gsr[rt] = s_a[r]; gdr[rt] = s_b[r]; }
    else { inv4[rt] = s_inv[r]; }
  }

  constexpr int NC1 = IS_EDGE ? 12 : 8;
  f32x4 acc[16];
#pragma unroll
  for (int i = 0; i < 16; ++i) { f32x4 z = {0.f,0.f,0.f,0.f}; acc[i] = z; }

  // -------- direct-global gather of layer-1 A fragments (8 consecutive fp32 / lane / rt) --------
  auto loadA = [&](int c, float4 (&p)[4][2]) {
    int reg = c >> 2;
    int co = ((c & 3) << 5) + kg * 8;
#pragma unroll
    for (int rt = 0; rt < 4; ++rt) {
      const float* q;
      if (IS_EDGE) {
        int idx = (reg == 0) ? gsr[rt] : (reg == 1) ? gdr[rt] : min(m0 + rt * 16 + l16, M - 1);
        q = ((reg == 2) ? edge_emb : node_emb) + (size_t)idx * 128 + co;
      } else {
        int idx = min(m0 + rt * 16 + l16, M - 1);
        q = ((reg == 0) ? node_emb : agg) + (size_t)idx * 128 + co;
      }
      p[rt][0] = *(const float4*)q;
      p[rt][1] = *(const float4*)(q + 4);
    }
  };

  auto l1comp = [&](int c, float4 (&p)[4][2], int bufi) {
    int reg = c >> 2;
    bf16x8 a[4];
#pragma unroll
    for (int rt = 0; rt < 4; ++rt) {
      float sc = (!IS_EDGE && reg == 1) ? inv4[rt] : 1.0f;
      const float* f0 = (const float*)p[rt];
#pragma unroll
      for (int e = 0; e < 8; ++e) a[rt][e] = f2bf(f0[e] * sc);
    }
    bf16x8 bfr[4];
#pragma unroll
    for (int ct = 0; ct < 4; ++ct)
      bfr[ct] = *(const bf16x8*)&Bs[bufi][(size_t)((w * 4 + ct) * 64 + lane) * 8];
#pragma unroll
    for (int rt = 0; rt < 4; ++rt)
#pragma unroll
      for (int ct = 0; ct < 4; ++ct)
        acc[rt * 4 + ct] =
            __builtin_amdgcn_mfma_f32_16x16x32_bf16(a[rt], bfr[ct], acc[rt * 4 + ct], 0, 0, 0);
  };

  // ---------------- layer 1 (K = NC1*32, N = 256), col-split waves ----------------
  float4 pa[4][2], pb[4][2];
  loadA(0, pa);
  int cur = 0;
  for (int kc = 0; kc < NC1; kc += 2) {
    stage((kc + 1 < NC1) ? w1p + (size_t)(kc + 1) * 8192 : w2p, Bs[cur ^ 1], tid, 1024);
    if (kc + 1 < NC1) loadA(kc + 1, pb);
    l1comp(kc, pa, cur);
    __syncthreads(); cur ^= 1;

    stage((kc + 2 < NC1) ? w1p + (size_t)(kc + 2) * 8192 : w2p, Bs[cur ^ 1], tid, 1024);
    if (kc + 2 < NC1) loadA(kc + 2, pa);
    l1comp(kc + 1, pb, cur);
    __syncthreads(); cur ^= 1;
  }
  // NOTE: last odd step staged W2 chunk 0 into Bs[cur]

  // H1 = relu(acc + b1)
#pragma unroll
  for (int ct = 0; ct < 4; ++ct) {
    int col = w * 64 + ct * 16 + l16;
    float bv = b1[col];
    int cbase = (col >> 5) * 2048 + ((col >> 3) & 3) * 8 + (col & 7);
#pragma unroll
    for (int rt = 0; rt < 4; ++rt) {
      f32x4 v = acc[rt * 4 + ct];
#pragma unroll
      for (int r = 0; r < 4; ++r) {
        int row = rt * 16 + kg * 4 + r;
        Hs[cbase + row * 32] = f2bf(fmaxf(v[r] + bv, 0.f));
      }
      f32x4 z = {0.f,0.f,0.f,0.f}; acc[rt * 4 + ct] = z;
    }
  }
  __syncthreads();

  // ---------------- layer 2 (K = 256, N = 256) ----------------
  for (int kc = 0; kc < 8; ++kc) {
    stage((kc < 7) ? w2p + (size_t)(kc + 1) * 8192 : w3p, Bs[cur ^ 1], tid, (kc < 7) ? 1024 : 512);
    bf16x8 a[4], bfr[4];
#pragma unroll
    for (int rt = 0; rt < 4; ++rt)
      a[rt] = *(const bf16x8*)&Hs[kc * 2048 + (rt * 16 + l16) * 32 + kg * 8];
#pragma unroll
    for (int ct = 0; ct < 4; ++ct)
      bfr[ct] = *(const bf16x8*)&Bs[cur][(size_t)((w * 4 + ct) * 64 + lane) * 8];
#pragma unroll
    for (int rt = 0; rt < 4; ++rt)
#pragma unroll
      for (int ct = 0; ct < 4; ++ct)
        acc[rt * 4 + ct] =
            __builtin_amdgcn_mfma_f32_16x16x32_bf16(a[rt], bfr[ct], acc[rt * 4 + ct], 0, 0, 0);
    __syncthreads(); cur ^= 1;
  }

  // H2 = relu(acc + b2)  (overwrite Hs; all reads completed at last barrier)
#pragma unroll
  for (int ct = 0; ct < 4; ++ct) {
    int col = w * 64 + ct * 16 + l16;
    float bv = b2[col];
    int cbase = (col >> 5) * 2048 + ((col >> 3) & 3) * 8 + (col & 7);
#pragma unroll
    for (int rt = 0; rt < 4; ++rt) {
      f32x4 v = acc[rt * 4 + ct];
#pragma unroll
      for (int r = 0; r < 4; ++r) {
        int row = rt * 16 + kg * 4 + r;
        Hs[cbase + row * 32] = f2bf(fmaxf(v[r] + bv, 0.f));
      }
      f32x4 z = {0.f,0.f,0.f,0.f}; acc[rt * 4 + ct] = z;
    }
  }
  __syncthreads();

  // ---------------- layer 3 (K = 256, N = 128), row-split waves ----------------
  for (int kc = 0; kc < 8; ++kc) {
    if (kc < 7) stage(w3p + (size_t)(kc + 1) * 4096, Bs[cur ^ 1], tid, 512);
    bf16x8 a = *(const bf16x8*)&Hs[kc * 2048 + (w * 16 + l16) * 32 + kg * 8];
#pragma unroll
    for (int f = 0; f < 8; ++f) {
      bf16x8 bfr = *(const bf16x8*)&Bs[cur][(size_t)(f * 64 + lane) * 8];
      acc[f] = __builtin_amdgcn_mfma_f32_16x16x32_bf16(a, bfr, acc[f], 0, 0, 0);
    }
    if (kc < 7) { __syncthreads(); cur ^= 1; }
  }

  // ---------------- epilogue: bias + LayerNorm + residual (+ agg atomics) ----------------
  float b3v[8], gv[8], bev[8];
#pragma unroll
  for (int f = 0; f < 8; ++f) {
    int col = f * 16 + l16;
    b3v[f] = b3[col]; gv[f] = gam[col]; bev[f] = bet[col];
  }
#pragma unroll
  for (int r = 0; r < 4; ++r) {
    int row = w * 16 + kg * 4 + r;
    int rg = m0 + row;
    float o[8], s1 = 0.f, s2 = 0.f;
#pragma unroll
    for (int f = 0; f < 8; ++f) { float x = acc[f][r] + b3v[f]; o[f] = x; s1 += x; s2 += x * x; }
#pragma unroll
    for (int m = 1; m <= 8; m <<= 1) { s1 += __shfl_xor(s1, m); s2 += __shfl_xor(s2, m); }
    float mu = s1 * (1.f / 128.f);
    float var = s2 * (1.f / 128.f) - mu * mu;
    float rs = rsqrtf(var + 1e-5f);
    if (rg < M) {
      const float* resid = (IS_EDGE ? edge_emb : node_emb) + (size_t)rg * 128;
      float* op = out_base + (size_t)rg * 128;
      int d = IS_EDGE ? dst[rg] : 0;
#pragma unroll
      for (int f = 0; f < 8; ++f) {
        int col = f * 16 + l16;
        float y = (o[f] - mu) * rs * gv[f] + bev[f] + resid[col];
        op[col] = y;
        if (IS_EDGE) atomicAdd(&agg[(size_t)d * 128 + col], y);
      }
    }
  }
}

extern "C" void kernel_launch(void* const* d_in, const int* in_sizes, int n_in,
                              void* d_out, int out_size, void* d_ws, size_t ws_size,
                              hipStream_t stream) {
  const float* node_emb = (const float*)d_in[0];
  const float* edge_emb = (const float*)d_in[1];
  const int*   src      = (const int*)d_in[2];
  const int*   dst      = (const int*)d_in[3];
  const float* eW1 = (const float*)d_in[5];
  const float* eb1 = (const float*)d_in[6];
  const float* eW2 = (const float*)d_in[7];
  const float* eb2 = (const float*)d_in[8];
  const float* eW3 = (const float*)d_in[9];
  const float* eb3 = (const float*)d_in[10];
  const float* eg  = (const float*)d_in[11];
  const float* ebt = (const float*)d_in[12];
  const float* nW1 = (const float*)d_in[13];
  const float* nb1 = (const float*)d_in[14];
  const float* nW2 = (const float*)d_in[15];
  const float* nb2 = (const float*)d_in[16];
  const float* nW3 = (const float*)d_in[17];
  const float* nb3 = (const float*)d_in[18];
  const float* ng  = (const float*)d_in[19];
  const float* nbt = (const float*)d_in[20];

  const int Nn = in_sizes[0] / 128;
  const int Ee = in_sizes[2];

  float* agg = (float*)d_ws;                    // Nn*128 f32
  float* cnt = agg + (size_t)Nn * 128;          // Nn f32
  short* wp  = (short*)(cnt + Nn);              // prepped bf16 weights
  short* eW1p = wp;                             // 12 chunks * 8192
  short* eW2p = wp + 98304;                     //  8 chunks * 8192
  short* eW3p = wp + 163840;                    //  8 chunks * 4096
  short* nW1p = wp + 196608;
  short* nW2p = wp + 262144;
  short* nW3p = wp + 327680;

  float* out_node = (float*)d_out;
  float* out_edge = out_node + (size_t)Nn * 128;

  hipMemsetAsync(d_ws, 0, ((size_t)Nn * 128 + Nn) * sizeof(float), stream);

  prep_kernel<<<48, 256, 0, stream>>>(eW1, eW1p, 384, 256);
  prep_kernel<<<32, 256, 0, stream>>>(eW2, eW2p, 256, 256);
  prep_kernel<<<16, 256, 0, stream>>>(eW3, eW3p, 256, 128);
  prep_kernel<<<32, 256, 0, stream>>>(nW1, nW1p, 256, 256);
  prep_kernel<<<32, 256, 0, stream>>>(nW2, nW2p, 256, 256);
  prep_kernel<<<16, 256, 0, stream>>>(nW3, nW3p, 256, 128);

  count_kernel<<<(Ee + 255) / 256, 256, 0, stream>>>(dst, cnt, Ee);

  mlp_kernel<true><<<(Ee + 63) / 64, 256, 0, stream>>>(
      node_emb, edge_emb, src, dst, eW1p, eW2p, eW3p,
      eb1, eb2, eb3, eg, ebt, agg, cnt, out_edge, Ee);
  mlp_kernel<false><<<(Nn + 63) / 64, 256, 0, stream>>>(
      node_emb, edge_emb, src, dst, nW1p, nW2p, nW3p,
      nb1, nb2, nb3, ng, nbt, agg, cnt, out_node, Nn);
}

// Round 3
// 908.726 us; speedup vs baseline: 1.6010x; 1.3085x over previous
//
#include <hip/hip_runtime.h>

typedef __attribute__((ext_vector_type(8))) short bf16x8;
typedef __attribute__((ext_vector_type(4))) float f32x4;

__device__ __forceinline__ short f2bf(float f) {
  union { float f; unsigned u; } v; v.f = f;
  unsigned r = v.u + 0x7fffu + ((v.u >> 16) & 1u);
  return (short)(r >> 16);
}

__device__ __forceinline__ void gld_lds16(const short* g, short* l) {
  __builtin_amdgcn_global_load_lds((const __attribute__((address_space(1))) unsigned*)g,
                                   (__attribute__((address_space(3))) unsigned*)l,
                                   16, 0, 0);
}

// copy nSlots 16-byte slots of pre-formatted weights into LDS (async, linear)
__device__ __forceinline__ void stage(const short* __restrict__ g, short* l, int tid, int nSlots) {
#pragma unroll
  for (int s0 = 0; s0 < 4; ++s0) {
    int s = s0 * 256 + tid;
    if (s < nSlots) gld_lds16(g + (size_t)s * 8, l + (size_t)s * 8);
  }
}

// W[K][N] fp32 -> bf16 fragment slots: slot s = (kc*(N/16)+f)*64 + lane, lane=(kg,l16)
// slot content: W[kc*32 + kg*8 + e][f*16 + l16], e = 0..7
__global__ void prep_kernel(const float* __restrict__ W, short* __restrict__ out, int K, int N) {
  int s = blockIdx.x * 256 + threadIdx.x;
  int NF = N >> 4;
  int total = (K >> 5) * NF * 64;
  if (s >= total) return;
  int l = s & 63, kcf = s >> 6;
  int kc = kcf / NF, f = kcf - kc * NF;
  int kg = l >> 4, l16 = l & 15;
  const float* p = W + (size_t)(kc * 32 + kg * 8) * N + f * 16 + l16;
  bf16x8 o;
#pragma unroll
  for (int e = 0; e < 8; ++e) o[e] = f2bf(p[(size_t)e * N]);
  *(bf16x8*)(out + (size_t)s * 8) = o;
}

// ---------------- CSR aggregation (replaces 82M f32 atomics) ----------------
__global__ void count_kernel(const int* __restrict__ dst, int* __restrict__ cnt, int E) {
  int i = blockIdx.x * 256 + threadIdx.x;
  if (i < E) atomicAdd(&cnt[dst[i]], 1);
}

__global__ __launch_bounds__(1024) void scan_kernel(const int* __restrict__ cnt,
                                                    int* __restrict__ off,
                                                    int* __restrict__ cursor, int N) {
  __shared__ int wsum[16];
  const int t = threadIdx.x;
  const int w = t >> 6, l = t & 63;
  int running = 0;
  for (int base = 0; base < N; base += 1024) {
    int i = base + t;
    int v = (i < N) ? cnt[i] : 0;
    int x = v;
#pragma unroll
    for (int d = 1; d < 64; d <<= 1) { int y = __shfl_up(x, d); if (l >= d) x += y; }
    if (l == 63) wsum[w] = x;
    __syncthreads();
    if (w == 0) {
      int s = (l < 16) ? wsum[l] : 0;
#pragma unroll
      for (int d = 1; d < 16; d <<= 1) { int y = __shfl_up(s, d); if (l >= d) s += y; }
      if (l < 16) wsum[l] = s;
    }
    __syncthreads();
    int total = wsum[15];
    int wo = (w > 0) ? wsum[w - 1] : 0;
    int excl = running + wo + x - v;
    if (i < N) { off[i] = excl; cursor[i] = excl; }
    running += total;
    __syncthreads();
  }
  if (t == 0) off[N] = running;
}

__global__ void scatter_kernel(const int* __restrict__ dst, int* __restrict__ cursor,
                               int* __restrict__ eidx, int E) {
  int e = blockIdx.x * 256 + threadIdx.x;
  if (e < E) {
    int p = atomicAdd(&cursor[dst[e]], 1);
    eidx[p] = e;
  }
}

// per-node gather-sum of new edge embeddings; writes mean directly
__global__ void agg_kernel(const float* __restrict__ edge_out, const int* __restrict__ eidx,
                           const int* __restrict__ off, float* __restrict__ agg, int N) {
  int n = blockIdx.x * 4 + (threadIdx.x >> 6);
  if (n >= N) return;
  int l = threadIdx.x & 63;
  int beg = off[n], end = off[n + 1];
  float ax = 0.f, ay = 0.f;
  int i = beg;
  for (; i + 4 <= end; i += 4) {
    int e0 = eidx[i], e1 = eidx[i + 1], e2 = eidx[i + 2], e3 = eidx[i + 3];
    float2 v0 = *(const float2*)(edge_out + (size_t)e0 * 128 + l * 2);
    float2 v1 = *(const float2*)(edge_out + (size_t)e1 * 128 + l * 2);
    float2 v2 = *(const float2*)(edge_out + (size_t)e2 * 128 + l * 2);
    float2 v3 = *(const float2*)(edge_out + (size_t)e3 * 128 + l * 2);
    ax += v0.x + v1.x + v2.x + v3.x;
    ay += v0.y + v1.y + v2.y + v3.y;
  }
  for (; i < end; ++i) {
    int e = eidx[i];
    float2 v = *(const float2*)(edge_out + (size_t)e * 128 + l * 2);
    ax += v.x; ay += v.y;
  }
  float inv = 1.0f / fmaxf((float)(end - beg), 1.0f);
  *(float2*)(agg + (size_t)n * 128 + l * 2) = make_float2(ax * inv, ay * inv);
}

// ---------------- fused 3-layer MLP + LN, row-split waves ----------------
template <int NF>
__device__ __forceinline__ void comp_chunk(bf16x8 a, const short* Bbuf, int lane, f32x4* ac) {
#pragma unroll
  for (int f = 0; f < NF; ++f) {
    bf16x8 b = *(const bf16x8*)&Bbuf[(size_t)(f * 64 + lane) * 8];
    ac[f] = __builtin_amdgcn_mfma_f32_16x16x32_bf16(a, b, ac[f], 0, 0, 0);
  }
}

struct F8 { float4 a, b; };

template <bool IS_EDGE>
__launch_bounds__(256, 2)
__global__ void mlp_kernel(const float* __restrict__ node_emb, const float* __restrict__ edge_emb,
                           const int* __restrict__ src, const int* __restrict__ dst,
                           const short* __restrict__ w1p, const short* __restrict__ w2p,
                           const short* __restrict__ w3p,
                           const float* __restrict__ b1, const float* __restrict__ b2,
                           const float* __restrict__ b3,
                           const float* __restrict__ gam, const float* __restrict__ bet,
                           const float* __restrict__ agg,
                           float* __restrict__ out_base, int M) {
  __shared__ short Bs[2][8192];  // 2 x 16 KiB double-buffered weight chunk (shared)
  __shared__ short Hs[16384];    // 32 KiB: 4 waves x 8 KiB wave-private H

  const int tid = threadIdx.x;
  const int m0 = blockIdx.x * 64;
  const int w = tid >> 6;
  const int lane = tid & 63;
  const int l16 = lane & 15;
  const int kg = lane >> 4;
  short* Hw = Hs + w * 4096;  // wave-private: 512 slots of 16B

  const int myrow = m0 + w * 16 + l16;  // row this lane gathers (row16 = l16)
  const int rc = min(myrow, M - 1);
  int gsr = 0, gdr = 0;
  if (IS_EDGE) { gsr = src[rc]; gdr = dst[rc]; }

  constexpr int NC1 = IS_EDGE ? 12 : 8;

  f32x4 acc[16];
#pragma unroll
  for (int i = 0; i < 16; ++i) { f32x4 z = {0.f, 0.f, 0.f, 0.f}; acc[i] = z; }

  auto gatherA = [&](int c) -> F8 {
    const float* q;
    if (IS_EDGE) {
      if (c < 4)      q = node_emb + (size_t)gsr * 128 + c * 32 + kg * 8;
      else if (c < 8) q = node_emb + (size_t)gdr * 128 + (c - 4) * 32 + kg * 8;
      else            q = edge_emb + (size_t)rc * 128 + (c - 8) * 32 + kg * 8;
    } else {
      if (c < 4)      q = node_emb + (size_t)rc * 128 + c * 32 + kg * 8;
      else            q = agg + (size_t)rc * 128 + (c - 4) * 32 + kg * 8;
    }
    F8 r;
    r.a = *(const float4*)q;
    r.b = *(const float4*)(q + 4);
    return r;
  };
  auto cvtA = [&](const F8& p) -> bf16x8 {
    bf16x8 a;
    const float* f = (const float*)&p;
#pragma unroll
    for (int e = 0; e < 8; ++e) a[e] = f2bf(f[e]);
    return a;
  };
  // H slot layout (wave-private): slot = kc*64 + kgH*16 + row16; bytes = H[row16][kc*32+kgH*8+e]
  auto writeH = [&](const float* __restrict__ bias, f32x4* ac) {
#pragma unroll
    for (int f = 0; f < 16; ++f) {
      int col = f * 16 + l16;
      float bv = bias[col];
      int slot = (f >> 1) * 64 + ((f & 1) * 2 + (l16 >> 3)) * 16 + kg * 4;
#pragma unroll
      for (int r = 0; r < 4; ++r)
        Hw[(size_t)(slot + r) * 8 + (l16 & 7)] = f2bf(fmaxf(ac[f][r] + bv, 0.f));
      f32x4 z = {0.f, 0.f, 0.f, 0.f};
      ac[f] = z;
    }
  };
  auto readHA = [&](int kc) -> bf16x8 {
    return *(const bf16x8*)&Hw[(size_t)(kc * 64 + kg * 16 + l16) * 8];
  };

  // ---- layer 1: K = NC1*32, N = 256 ----
  stage(w1p, Bs[0], tid, 1024);
  F8 pa = gatherA(0);
  __syncthreads();
  int cur = 0;
  for (int kc = 0; kc < NC1; ++kc) {
    const short* nxt = (kc + 1 < NC1) ? w1p + (size_t)(kc + 1) * 8192 : w2p;
    stage(nxt, Bs[cur ^ 1], tid, 1024);
    F8 pn = pa;
    if (kc + 1 < NC1) pn = gatherA(kc + 1);
    bf16x8 a = cvtA(pa);
    comp_chunk<16>(a, Bs[cur], lane, acc);
    __syncthreads();
    cur ^= 1;
    pa = pn;
  }
  writeH(b1, acc);  // H1 (wave-private, no barrier)

  // ---- layer 2: K = 256, N = 256 ----
  for (int kc = 0; kc < 8; ++kc) {
    const short* nxt = (kc < 7) ? w2p + (size_t)(kc + 1) * 8192 : w3p;
    stage(nxt, Bs[cur ^ 1], tid, (kc < 7) ? 1024 : 512);
    bf16x8 a = readHA(kc);
    comp_chunk<16>(a, Bs[cur], lane, acc);
    __syncthreads();
    cur ^= 1;
  }
  writeH(b2, acc);  // H2 overwrites H1 (own region fully read by now)

  // ---- layer 3: K = 256, N = 128 ----
  for (int kc = 0; kc < 8; ++kc) {
    if (kc < 7) stage(w3p + (size_t)(kc + 1) * 4096, Bs[cur ^ 1], tid, 512);
    bf16x8 a = readHA(kc);
    comp_chunk<8>(a, Bs[cur], lane, acc);
    if (kc < 7) { __syncthreads(); cur ^= 1; }
  }

  // ---- epilogue: bias + LayerNorm + residual ----
  float b3v[8], gv[8], bev[8];
#pragma unroll
  for (int f = 0; f < 8; ++f) {
    int col = f * 16 + l16;
    b3v[f] = b3[col]; gv[f] = gam[col]; bev[f] = bet[col];
  }
#pragma unroll
  for (int r = 0; r < 4; ++r) {
    int rg = m0 + w * 16 + kg * 4 + r;
    float o[8], s1 = 0.f, s2 = 0.f;
#pragma unroll
    for (int f = 0; f < 8; ++f) {
      float x = acc[f][r] + b3v[f];
      o[f] = x; s1 += x; s2 += x * x;
    }
#pragma unroll
    for (int m = 1; m <= 8; m <<= 1) { s1 += __shfl_xor(s1, m); s2 += __shfl_xor(s2, m); }
    float mu = s1 * (1.f / 128.f);
    float var = s2 * (1.f / 128.f) - mu * mu;
    float rs = rsqrtf(var + 1e-5f);
    if (rg < M) {
      const float* resid = (IS_EDGE ? edge_emb : node_emb) + (size_t)rg * 128;
      float* op = out_base + (size_t)rg * 128;
#pragma unroll
      for (int f = 0; f < 8; ++f) {
        int col = f * 16 + l16;
        op[col] = (o[f] - mu) * rs * gv[f] + bev[f] + resid[col];
      }
    }
  }
}

extern "C" void kernel_launch(void* const* d_in, const int* in_sizes, int n_in,
                              void* d_out, int out_size, void* d_ws, size_t ws_size,
                              hipStream_t stream) {
  const float* node_emb = (const float*)d_in[0];
  const float* edge_emb = (const float*)d_in[1];
  const int*   src      = (const int*)d_in[2];
  const int*   dst      = (const int*)d_in[3];
  const float* eW1 = (const float*)d_in[5];
  const float* eb1 = (const float*)d_in[6];
  const float* eW2 = (const float*)d_in[7];
  const float* eb2 = (const float*)d_in[8];
  const float* eW3 = (const float*)d_in[9];
  const float* eb3 = (const float*)d_in[10];
  const float* eg  = (const float*)d_in[11];
  const float* ebt = (const float*)d_in[12];
  const float* nW1 = (const float*)d_in[13];
  const float* nb1 = (const float*)d_in[14];
  const float* nW2 = (const float*)d_in[15];
  const float* nb2 = (const float*)d_in[16];
  const float* nW3 = (const float*)d_in[17];
  const float* nb3 = (const float*)d_in[18];
  const float* ng  = (const float*)d_in[19];
  const float* nbt = (const float*)d_in[20];

  const int Nn = in_sizes[0] / 128;
  const int Ee = in_sizes[2];

  char* ws = (char*)d_ws;
  float* agg  = (float*)ws;  ws += (size_t)Nn * 128 * 4;
  int* cnt_i  = (int*)ws;    ws += (size_t)Nn * 4;
  int* cursor = (int*)ws;    ws += (size_t)Nn * 4;
  int* offv   = (int*)ws;    ws += (size_t)(Nn + 1) * 4;
  int* eidx   = (int*)ws;    ws += (size_t)Ee * 4;
  ws = (char*)(((uintptr_t)ws + 15) & ~(uintptr_t)15);
  short* wp = (short*)ws;
  short* eW1p = wp;            // 12 chunks * 8192 shorts
  short* eW2p = wp + 98304;    //  8 * 8192
  short* eW3p = wp + 163840;   //  8 * 4096
  short* nW1p = wp + 196608;   //  8 * 8192
  short* nW2p = wp + 262144;   //  8 * 8192
  short* nW3p = wp + 327680;   //  8 * 4096

  float* out_node = (float*)d_out;
  float* out_edge = out_node + (size_t)Nn * 128;

  hipMemsetAsync(cnt_i, 0, (size_t)Nn * 4, stream);

  prep_kernel<<<48, 256, 0, stream>>>(eW1, eW1p, 384, 256);
  prep_kernel<<<32, 256, 0, stream>>>(eW2, eW2p, 256, 256);
  prep_kernel<<<16, 256, 0, stream>>>(eW3, eW3p, 256, 128);
  prep_kernel<<<32, 256, 0, stream>>>(nW1, nW1p, 256, 256);
  prep_kernel<<<32, 256, 0, stream>>>(nW2, nW2p, 256, 256);
  prep_kernel<<<16, 256, 0, stream>>>(nW3, nW3p, 256, 128);

  count_kernel<<<(Ee + 255) / 256, 256, 0, stream>>>(dst, cnt_i, Ee);
  scan_kernel<<<1, 1024, 0, stream>>>(cnt_i, offv, cursor, Nn);
  scatter_kernel<<<(Ee + 255) / 256, 256, 0, stream>>>(dst, cursor, eidx, Ee);

  mlp_kernel<true><<<(Ee + 63) / 64, 256, 0, stream>>>(
      node_emb, edge_emb, src, dst, eW1p, eW2p, eW3p,
      eb1, eb2, eb3, eg, ebt, agg, out_edge, Ee);

  agg_kernel<<<(Nn + 3) / 4, 256, 0, stream>>>(out_edge, eidx, offv, agg, Nn);

  mlp_kernel<false><<<(Nn + 63) / 64, 256, 0, stream>>>(
      node_emb, edge_emb, src, dst, nW1p, nW2p, nW3p,
      nb1, nb2, nb3, ng, nbt, agg, out_node, Nn);
}

// Round 4
// 817.304 us; speedup vs baseline: 1.7800x; 1.1119x over previous
//
#include <hip/hip_runtime.h>
#include <hip/hip_bf16.h>

typedef __attribute__((ext_vector_type(8))) short bf16x8;
typedef __attribute__((ext_vector_type(4))) float f32x4;

__device__ __forceinline__ short f2bf(float f) {
  union { __hip_bfloat16 h; short s; } u;
  u.h = __float2bfloat16(f);
  return u.s;
}

__device__ __forceinline__ void gld_lds16(const short* g, short* l) {
  __builtin_amdgcn_global_load_lds((const __attribute__((address_space(1))) unsigned*)g,
                                   (__attribute__((address_space(3))) unsigned*)l,
                                   16, 0, 0);
}

template <int NSLOTS>
__device__ __forceinline__ void stage(const short* __restrict__ g, short* l, int tid) {
#pragma unroll
  for (int s0 = 0; s0 < NSLOTS / 256; ++s0) {
    int s = s0 * 256 + tid;
    gld_lds16(g + (size_t)s * 8, l + (size_t)s * 8);
  }
}

// W[K][N] fp32 -> bf16 fragment slots: slot s = (kc*(N/16)+f)*64 + lane, lane=(kg,l16)
// slot content: W[kc*32 + kg*8 + e][f*16 + l16], e = 0..7
__global__ void prep_kernel(const float* __restrict__ W, short* __restrict__ out, int K, int N) {
  int s = blockIdx.x * 256 + threadIdx.x;
  int NF = N >> 4;
  int total = (K >> 5) * NF * 64;
  if (s >= total) return;
  int l = s & 63, kcf = s >> 6;
  int kc = kcf / NF, f = kcf - kc * NF;
  int kg = l >> 4, l16 = l & 15;
  const float* p = W + (size_t)(kc * 32 + kg * 8) * N + f * 16 + l16;
  bf16x8 o;
#pragma unroll
  for (int e = 0; e < 8; ++e) o[e] = f2bf(p[(size_t)e * N]);
  *(bf16x8*)(out + (size_t)s * 8) = o;
}

// ---------------- CSR aggregation ----------------
__global__ void count_kernel(const int* __restrict__ dst, int* __restrict__ cnt, int E) {
  int i = blockIdx.x * 256 + threadIdx.x;
  if (i < E) atomicAdd(&cnt[dst[i]], 1);
}

__global__ __launch_bounds__(1024) void scan_kernel(const int* __restrict__ cnt,
                                                    int* __restrict__ off,
                                                    int* __restrict__ cursor, int N) {
  __shared__ int wsum[16];
  const int t = threadIdx.x;
  const int w = t >> 6, l = t & 63;
  int running = 0;
  for (int base = 0; base < N; base += 1024) {
    int i = base + t;
    int v = (i < N) ? cnt[i] : 0;
    int x = v;
#pragma unroll
    for (int d = 1; d < 64; d <<= 1) { int y = __shfl_up(x, d); if (l >= d) x += y; }
    if (l == 63) wsum[w] = x;
    __syncthreads();
    if (w == 0) {
      int s = (l < 16) ? wsum[l] : 0;
#pragma unroll
      for (int d = 1; d < 16; d <<= 1) { int y = __shfl_up(s, d); if (l >= d) s += y; }
      if (l < 16) wsum[l] = s;
    }
    __syncthreads();
    int total = wsum[15];
    int wo = (w > 0) ? wsum[w - 1] : 0;
    int excl = running + wo + x - v;
    if (i < N) { off[i] = excl; cursor[i] = excl; }
    running += total;
    __syncthreads();
  }
  if (t == 0) off[N] = running;
}

__global__ void scatter_kernel(const int* __restrict__ dst, int* __restrict__ cursor,
                               int* __restrict__ eidx, int E) {
  int e = blockIdx.x * 256 + threadIdx.x;
  if (e < E) {
    int p = atomicAdd(&cursor[dst[e]], 1);
    eidx[p] = e;
  }
}

__global__ void agg_kernel(const float* __restrict__ edge_out, const int* __restrict__ eidx,
                           const int* __restrict__ off, float* __restrict__ agg, int N) {
  int n = blockIdx.x * 4 + (threadIdx.x >> 6);
  if (n >= N) return;
  int l = threadIdx.x & 63;
  int beg = off[n], end = off[n + 1];
  float ax = 0.f, ay = 0.f;
  int i = beg;
  for (; i + 4 <= end; i += 4) {
    int e0 = eidx[i], e1 = eidx[i + 1], e2 = eidx[i + 2], e3 = eidx[i + 3];
    float2 v0 = *(const float2*)(edge_out + (size_t)e0 * 128 + l * 2);
    float2 v1 = *(const float2*)(edge_out + (size_t)e1 * 128 + l * 2);
    float2 v2 = *(const float2*)(edge_out + (size_t)e2 * 128 + l * 2);
    float2 v3 = *(const float2*)(edge_out + (size_t)e3 * 128 + l * 2);
    ax += v0.x + v1.x + v2.x + v3.x;
    ay += v0.y + v1.y + v2.y + v3.y;
  }
  for (; i < end; ++i) {
    int e = eidx[i];
    float2 v = *(const float2*)(edge_out + (size_t)e * 128 + l * 2);
    ax += v.x; ay += v.y;
  }
  float inv = 1.0f / fmaxf((float)(end - beg), 1.0f);
  *(float2*)(agg + (size_t)n * 128 + l * 2) = make_float2(ax * inv, ay * inv);
}

struct F8 { float4 a, b; };

// ---------------- fused 3-layer MLP + LN ----------------
// Layers 1-2: col-split (wave w owns cols w*64..w*64+63, all 64 rows; M_rep=4, NF=4)
// Layer 3:    row-split (wave w owns rows w*16..w*16+15, all 128 cols)
// H LDS layout: slot(row, cg) = row*32 + (cg ^ (row&7)), cg = col>>3  (conflict-free b128 reads)
// Layer-1 A chunks (64 rows x 32 cols bf16) overlay Hs slots 0..511, double-buffered.
template <bool IS_EDGE>
__launch_bounds__(256, 2)
__global__ void mlp_kernel(const float* __restrict__ node_emb, const float* __restrict__ edge_emb,
                           const int* __restrict__ src, const int* __restrict__ dst,
                           const short* __restrict__ w1p, const short* __restrict__ w2p,
                           const short* __restrict__ w3p,
                           const float* __restrict__ b1, const float* __restrict__ b2,
                           const float* __restrict__ b3,
                           const float* __restrict__ gam, const float* __restrict__ bet,
                           const float* __restrict__ agg,
                           float* __restrict__ out_base, int M) {
  __shared__ short Bs[2][8192];  // 2 x 16 KiB weight chunk (double-buffered)
  __shared__ short Hs[16384];    // 32 KiB activations; slots 0..511 double as A-chunk bufs in L1

  const int tid = threadIdx.x;
  const int bid = blockIdx.x;
  const int m0 = bid * 64;
  const int w = tid >> 6, lane = tid & 63, l16 = lane & 15, kg = lane >> 4;

  constexpr int NC1 = IS_EDGE ? 12 : 8;
  const int r1 = bid % NC1;
  const int r2 = bid & 7;
  auto c1 = [&](int i) { int c = r1 + i; return c < NC1 ? c : c - NC1; };
  auto c2 = [&](int i) { return (r2 + i) & 7; };

  // gather role: thread stages row (tid>>2), 8 cols at (tid&3)*8 within the 32-col chunk
  const int grow = tid >> 2;
  const int gco = (tid & 3) * 8;
  const int grc = min(m0 + grow, M - 1);
  const int aslot = (grow >> 4) * 64 + (tid & 3) * 16 + (grow & 15);
  int gsr = 0, gdr = 0;
  if (IS_EDGE) { gsr = src[grc]; gdr = dst[grc]; }

  // preload biases / LN params
  float b1v[4], b2v[4];
#pragma unroll
  for (int ct = 0; ct < 4; ++ct) {
    int col = w * 64 + ct * 16 + l16;
    b1v[ct] = b1[col];
    b2v[ct] = b2[col];
  }
  float b3v[8], gv[8], bev[8];
#pragma unroll
  for (int f = 0; f < 8; ++f) {
    int col = f * 16 + l16;
    b3v[f] = b3[col]; gv[f] = gam[col]; bev[f] = bet[col];
  }

  f32x4 acc[16];
#pragma unroll
  for (int i = 0; i < 16; ++i) { f32x4 z = {0.f, 0.f, 0.f, 0.f}; acc[i] = z; }

  auto gatherA = [&](int c) -> F8 {
    const float* q;
    if (IS_EDGE) {
      if (c < 4)      q = node_emb + (size_t)gsr * 128 + c * 32 + gco;
      else if (c < 8) q = node_emb + (size_t)gdr * 128 + (c - 4) * 32 + gco;
      else            q = edge_emb + (size_t)grc * 128 + (c - 8) * 32 + gco;
    } else {
      if (c < 4)      q = node_emb + (size_t)grc * 128 + c * 32 + gco;
      else            q = agg + (size_t)grc * 128 + (c - 4) * 32 + gco;
    }
    F8 r;
    r.a = *(const float4*)q;
    r.b = *(const float4*)(q + 4);
    return r;
  };
  auto writeA = [&](const F8& p, int buf) {
    float tmp[8];
    *(float4*)tmp = p.a; *(float4*)(tmp + 4) = p.b;
    bf16x8 o;
#pragma unroll
    for (int e = 0; e < 8; ++e) o[e] = f2bf(tmp[e]);
    *(bf16x8*)&Hs[(size_t)(buf * 256 + aslot) * 8] = o;
  };
  // col-split compute: A frags from Abase (256 slots), B frags (wave's 4) from Bbase
  auto compNS = [&](const short* Abase, const short* Bbase) {
    bf16x8 a[4], b[4];
#pragma unroll
    for (int rt = 0; rt < 4; ++rt) a[rt] = *(const bf16x8*)&Abase[(size_t)(rt * 64 + kg * 16 + l16) * 8];
#pragma unroll
    for (int ct = 0; ct < 4; ++ct) b[ct] = *(const bf16x8*)&Bbase[(size_t)((w * 4 + ct) * 64 + lane) * 8];
#pragma unroll
    for (int rt = 0; rt < 4; ++rt)
#pragma unroll
      for (int ct = 0; ct < 4; ++ct)
        acc[rt * 4 + ct] = __builtin_amdgcn_mfma_f32_16x16x32_bf16(a[rt], b[ct], acc[rt * 4 + ct], 0, 0, 0);
  };
  // col-split compute with A frags from swizzled H
  auto compH = [&](int kc, const short* Bbase) {
    bf16x8 a[4], b[4];
#pragma unroll
    for (int rt = 0; rt < 4; ++rt) {
      int row = rt * 16 + l16, cg = kc * 4 + kg;
      a[rt] = *(const bf16x8*)&Hs[(size_t)(row * 32 + (cg ^ (row & 7))) * 8];
    }
#pragma unroll
    for (int ct = 0; ct < 4; ++ct) b[ct] = *(const bf16x8*)&Bbase[(size_t)((w * 4 + ct) * 64 + lane) * 8];
#pragma unroll
    for (int rt = 0; rt < 4; ++rt)
#pragma unroll
      for (int ct = 0; ct < 4; ++ct)
        acc[rt * 4 + ct] = __builtin_amdgcn_mfma_f32_16x16x32_bf16(a[rt], b[ct], acc[rt * 4 + ct], 0, 0, 0);
  };
  // col-split H write (relu + bias), zero acc
  auto writeH = [&](const float* bias4) {
#pragma unroll
    for (int ct = 0; ct < 4; ++ct) {
      int col = w * 64 + ct * 16 + l16;
      int cg = col >> 3, el = col & 7;
      float bv = bias4[ct];
#pragma unroll
      for (int rt = 0; rt < 4; ++rt) {
        f32x4 v = acc[rt * 4 + ct];
#pragma unroll
        for (int q = 0; q < 4; ++q) {
          int row = rt * 16 + kg * 4 + q;
          Hs[(size_t)(row * 32 + (cg ^ (row & 7))) * 8 + el] = f2bf(fmaxf(v[q] + bv, 0.f));
        }
        f32x4 z = {0.f, 0.f, 0.f, 0.f};
        acc[rt * 4 + ct] = z;
      }
    }
  };

  // ---- layer 1 (K = NC1*32, N = 256): counted-vmcnt pipeline ----
  F8 p0 = gatherA(c1(0));
  stage<1024>(w1p + (size_t)c1(0) * 8192, Bs[0], tid);
  F8 sHold = gatherA(c1(1));
  writeA(p0, 0);
  __syncthreads();

  int curB = 0, curA = 0;
#pragma unroll
  for (int i = 0; i < NC1; ++i) {
    const short* nxt = (i + 1 < NC1) ? w1p + (size_t)c1(i + 1) * 8192
                                     : w2p + (size_t)c2(0) * 8192;
    stage<1024>(nxt, Bs[curB ^ 1], tid);
    __builtin_amdgcn_sched_barrier(0);
    F8 pin = sHold;
    if (i + 2 < NC1) pin = gatherA(c1(i + 2));
    __builtin_amdgcn_sched_barrier(0);
    compNS(&Hs[(size_t)curA * 2048], Bs[curB]);
    if (i + 1 < NC1) writeA(sHold, curA ^ 1);
    if (i + 2 < NC1) asm volatile("s_waitcnt vmcnt(2) lgkmcnt(0)" ::: "memory");
    else             asm volatile("s_waitcnt vmcnt(0) lgkmcnt(0)" ::: "memory");
    __builtin_amdgcn_s_barrier();
    __builtin_amdgcn_sched_barrier(0);
    curB ^= 1;
    if (i + 1 < NC1) curA ^= 1;
    sHold = pin;
  }
  writeH(b1v);  // H1
  __syncthreads();

  // ---- layer 2 (K = 256, N = 256) ----
#pragma unroll
  for (int j = 0; j < 8; ++j) {
    if (j < 7) stage<1024>(w2p + (size_t)c2(j + 1) * 8192, Bs[curB ^ 1], tid);
    else       stage<512>(w3p + (size_t)c2(0) * 4096, Bs[curB ^ 1], tid);
    compH(c2(j), Bs[curB]);
    __syncthreads();
    curB ^= 1;
  }
  writeH(b2v);  // H2
  __syncthreads();

  // ---- layer 3 (K = 256, N = 128), row-split ----
#pragma unroll
  for (int j = 0; j < 8; ++j) {
    if (j < 7) stage<512>(w3p + (size_t)c2(j + 1) * 4096, Bs[curB ^ 1], tid);
    {
      int row = w * 16 + l16, cg = c2(j) * 4 + kg;
      bf16x8 a = *(const bf16x8*)&Hs[(size_t)(row * 32 + (cg ^ (row & 7))) * 8];
#pragma unroll
      for (int f = 0; f < 8; ++f) {
        bf16x8 b = *(const bf16x8*)&Bs[curB][(size_t)(f * 64 + lane) * 8];
        acc[f] = __builtin_amdgcn_mfma_f32_16x16x32_bf16(a, b, acc[f], 0, 0, 0);
      }
    }
    if (j < 7) { __syncthreads(); curB ^= 1; }
  }

  // ---- epilogue: bias + LayerNorm + residual ----
#pragma unroll
  for (int q = 0; q < 4; ++q) {
    int rg = m0 + w * 16 + kg * 4 + q;
    float o[8], s1 = 0.f, s2 = 0.f;
#pragma unroll
    for (int f = 0; f < 8; ++f) {
      float x = acc[f][q] + b3v[f];
      o[f] = x; s1 += x; s2 += x * x;
    }
#pragma unroll
    for (int m = 1; m <= 8; m <<= 1) { s1 += __shfl_xor(s1, m); s2 += __shfl_xor(s2, m); }
    float mu = s1 * (1.f / 128.f);
    float var = s2 * (1.f / 128.f) - mu * mu;
    float rs = rsqrtf(var + 1e-5f);
    if (rg < M) {
      const float* resid = (IS_EDGE ? edge_emb : node_emb) + (size_t)rg * 128;
      float* op = out_base + (size_t)rg * 128;
#pragma unroll
      for (int f = 0; f < 8; ++f) {
        int col = f * 16 + l16;
        op[col] = (o[f] - mu) * rs * gv[f] + bev[f] + resid[col];
      }
    }
  }
}

extern "C" void kernel_launch(void* const* d_in, const int* in_sizes, int n_in,
                              void* d_out, int out_size, void* d_ws, size_t ws_size,
                              hipStream_t stream) {
  const float* node_emb = (const float*)d_in[0];
  const float* edge_emb = (const float*)d_in[1];
  const int*   src      = (const int*)d_in[2];
  const int*   dst      = (const int*)d_in[3];
  const float* eW1 = (const float*)d_in[5];
  const float* eb1 = (const float*)d_in[6];
  const float* eW2 = (const float*)d_in[7];
  const float* eb2 = (const float*)d_in[8];
  const float* eW3 = (const float*)d_in[9];
  const float* eb3 = (const float*)d_in[10];
  const float* eg  = (const float*)d_in[11];
  const float* ebt = (const float*)d_in[12];
  const float* nW1 = (const float*)d_in[13];
  const float* nb1 = (const float*)d_in[14];
  const float* nW2 = (const float*)d_in[15];
  const float* nb2 = (const float*)d_in[16];
  const float* nW3 = (const float*)d_in[17];
  const float* nb3 = (const float*)d_in[18];
  const float* ng  = (const float*)d_in[19];
  const float* nbt = (const float*)d_in[20];

  const int Nn = in_sizes[0] / 128;
  const int Ee = in_sizes[2];

  char* ws = (char*)d_ws;
  float* agg  = (float*)ws;  ws += (size_t)Nn * 128 * 4;
  int* cnt_i  = (int*)ws;    ws += (size_t)Nn * 4;
  int* cursor = (int*)ws;    ws += (size_t)Nn * 4;
  int* offv   = (int*)ws;    ws += (size_t)(Nn + 1) * 4;
  int* eidx   = (int*)ws;    ws += (size_t)Ee * 4;
  ws = (char*)(((uintptr_t)ws + 15) & ~(uintptr_t)15);
  short* wp = (short*)ws;
  short* eW1p = wp;            // 12 chunks * 8192 shorts
  short* eW2p = wp + 98304;    //  8 * 8192
  short* eW3p = wp + 163840;   //  8 * 4096
  short* nW1p = wp + 196608;   //  8 * 8192
  short* nW2p = wp + 262144;   //  8 * 8192
  short* nW3p = wp + 327680;   //  8 * 4096

  float* out_node = (float*)d_out;
  float* out_edge = out_node + (size_t)Nn * 128;

  hipMemsetAsync(cnt_i, 0, (size_t)Nn * 4, stream);

  prep_kernel<<<48, 256, 0, stream>>>(eW1, eW1p, 384, 256);
  prep_kernel<<<32, 256, 0, stream>>>(eW2, eW2p, 256, 256);
  prep_kernel<<<16, 256, 0, stream>>>(eW3, eW3p, 256, 128);
  prep_kernel<<<32, 256, 0, stream>>>(nW1, nW1p, 256, 256);
  prep_kernel<<<32, 256, 0, stream>>>(nW2, nW2p, 256, 256);
  prep_kernel<<<16, 256, 0, stream>>>(nW3, nW3p, 256, 128);

  count_kernel<<<(Ee + 255) / 256, 256, 0, stream>>>(dst, cnt_i, Ee);
  scan_kernel<<<1, 1024, 0, stream>>>(cnt_i, offv, cursor, Nn);
  scatter_kernel<<<(Ee + 255) / 256, 256, 0, stream>>>(dst, cursor, eidx, Ee);

  mlp_kernel<true><<<(Ee + 63) / 64, 256, 0, stream>>>(
      node_emb, edge_emb, src, dst, eW1p, eW2p, eW3p,
      eb1, eb2, eb3, eg, ebt, agg, out_edge, Ee);

  agg_kernel<<<(Nn + 3) / 4, 256, 0, stream>>>(out_edge, eidx, offv, agg, Nn);

  mlp_kernel<false><<<(Nn + 63) / 64, 256, 0, stream>>>(
      node_emb, edge_emb, src, dst, nW1p, nW2p, nW3p,
      nb1, nb2, nb3, ng, nbt, agg, out_node, Nn);
}

// Round 5
// 751.757 us; speedup vs baseline: 1.9352x; 1.0872x over previous
//
#include <hip/hip_runtime.h>
#include <hip/hip_bf16.h>

typedef __attribute__((ext_vector_type(8))) short bf16x8;
typedef __attribute__((ext_vector_type(4))) short s16x4;
typedef __attribute__((ext_vector_type(4))) float f32x4;

__device__ __forceinline__ short f2bf(float f) {
  union { __hip_bfloat16 h; short s; } u;
  u.h = __float2bfloat16(f);
  return u.s;
}

__device__ __forceinline__ void gld_lds16(const short* g, short* l) {
  __builtin_amdgcn_global_load_lds((const __attribute__((address_space(1))) unsigned*)g,
                                   (__attribute__((address_space(3))) unsigned*)l,
                                   16, 0, 0);
}

#define BARX(N) asm volatile("s_waitcnt vmcnt(" #N ") lgkmcnt(0)\ns_barrier" ::: "memory")
#define BARLG() asm volatile("s_waitcnt lgkmcnt(0)\ns_barrier" ::: "memory")

// W[K][N] fp32 -> bf16 fragment slots: slot s = (kc*(N/16)+f)*64 + lane, lane=(kg,l16)
// content: W[k(kc*32+kg*8+e)][f*16+l16].  PERM: k-hat -> k column permutation matching
// the H storage order: k = (kh & ~63) | ((kh&3)<<4) | ((kh>>2)&15)
template <bool PERM>
__global__ void prep_kernel(const float* __restrict__ W, short* __restrict__ out, int K, int N) {
  int s = blockIdx.x * 256 + threadIdx.x;
  int NF = N >> 4;
  int total = (K >> 5) * NF * 64;
  if (s >= total) return;
  int l = s & 63, kcf = s >> 6;
  int kc = kcf / NF, f = kcf - kc * NF;
  int kg = l >> 4, l16 = l & 15;
  bf16x8 o;
#pragma unroll
  for (int e = 0; e < 8; ++e) {
    int kh = kc * 32 + kg * 8 + e;
    int k = PERM ? ((kh & ~63) | ((kh & 3) << 4) | ((kh >> 2) & 15)) : kh;
    o[e] = f2bf(W[(size_t)k * N + f * 16 + l16]);
  }
  *(bf16x8*)(out + (size_t)s * 8) = o;
}

// ---------------- CSR aggregation ----------------
__global__ void count_kernel(const int* __restrict__ dst, int* __restrict__ cnt, int E) {
  int i = blockIdx.x * 256 + threadIdx.x;
  if (i < E) atomicAdd(&cnt[dst[i]], 1);
}

__global__ __launch_bounds__(1024) void scan_kernel(const int* __restrict__ cnt,
                                                    int* __restrict__ off,
                                                    int* __restrict__ cursor, int N) {
  __shared__ int wsum[16];
  const int t = threadIdx.x;
  const int w = t >> 6, l = t & 63;
  int running = 0;
  for (int base = 0; base < N; base += 1024) {
    int i = base + t;
    int v = (i < N) ? cnt[i] : 0;
    int x = v;
#pragma unroll
    for (int d = 1; d < 64; d <<= 1) { int y = __shfl_up(x, d); if (l >= d) x += y; }
    if (l == 63) wsum[w] = x;
    __syncthreads();
    if (w == 0) {
      int s = (l < 16) ? wsum[l] : 0;
#pragma unroll
      for (int d = 1; d < 16; d <<= 1) { int y = __shfl_up(s, d); if (l >= d) s += y; }
      if (l < 16) wsum[l] = s;
    }
    __syncthreads();
    int total = wsum[15];
    int wo = (w > 0) ? wsum[w - 1] : 0;
    int excl = running + wo + x - v;
    if (i < N) { off[i] = excl; cursor[i] = excl; }
    running += total;
    __syncthreads();
  }
  if (t == 0) off[N] = running;
}

__global__ void scatter_kernel(const int* __restrict__ dst, int* __restrict__ cursor,
                               int* __restrict__ eidx, int E) {
  int e = blockIdx.x * 256 + threadIdx.x;
  if (e < E) {
    int p = atomicAdd(&cursor[dst[e]], 1);
    eidx[p] = e;
  }
}

__global__ void agg_kernel(const float* __restrict__ edge_out, const int* __restrict__ eidx,
                           const int* __restrict__ off, float* __restrict__ agg, int N) {
  int n = blockIdx.x * 4 + (threadIdx.x >> 6);
  if (n >= N) return;
  int l = threadIdx.x & 63;
  int beg = off[n], end = off[n + 1];
  float ax = 0.f, ay = 0.f;
  int i = beg;
  for (; i + 4 <= end; i += 4) {
    int e0 = eidx[i], e1 = eidx[i + 1], e2 = eidx[i + 2], e3 = eidx[i + 3];
    float2 v0 = *(const float2*)(edge_out + (size_t)e0 * 128 + l * 2);
    float2 v1 = *(const float2*)(edge_out + (size_t)e1 * 128 + l * 2);
    float2 v2 = *(const float2*)(edge_out + (size_t)e2 * 128 + l * 2);
    float2 v3 = *(const float2*)(edge_out + (size_t)e3 * 128 + l * 2);
    ax += v0.x + v1.x + v2.x + v3.x;
    ay += v0.y + v1.y + v2.y + v3.y;
  }
  for (; i < end; ++i) {
    int e = eidx[i];
    float2 v = *(const float2*)(edge_out + (size_t)e * 128 + l * 2);
    ax += v.x; ay += v.y;
  }
  float inv = 1.0f / fmaxf((float)(end - beg), 1.0f);
  *(float2*)(agg + (size_t)n * 128 + l * 2) = make_float2(ax * inv, ay * inv);
}

struct F8 { float4 a, b; };

// ---------------- fused 3-layer MLP + LN, BM=128, 512 threads, 128 KB dyn LDS ----------------
// L1/L2: waves 2(row-half) x 4(col-quarter), each 64 rows x 64 cols (4x4 frags).
// L3: row-split, wave w owns rows w*16..+15, all 128 cols.
// H storage: addr_shorts(row, ch) = row*256 + (ch ^ ((row&7)<<3)); stored col at position ch
// (within each 64-block): c = ((ch&3)<<4) | ((ch>>2)&15)  -- matches PERM'd W2/W3 K-order.
template <bool IS_EDGE>
__launch_bounds__(512, 2)
__global__ void mlp_kernel(const float* __restrict__ node_emb, const float* __restrict__ edge_emb,
                           const int* __restrict__ src, const int* __restrict__ dst,
                           const short* __restrict__ wAll,
                           const float* __restrict__ b1, const float* __restrict__ b2,
                           const float* __restrict__ b3,
                           const float* __restrict__ gam, const float* __restrict__ bet,
                           const float* __restrict__ agg,
                           float* __restrict__ out_base, int M) {
  extern __shared__ short smem[];
  short* BsBase = smem;            // 3 x 8192 shorts (3 x 16 KB), triple-buffered stage
  short* AsBase = smem + 24576;    // 2 x 4096 shorts (2 x 8 KB), L1 A chunks
  short* Hs     = smem + 32768;    // 32768 shorts (64 KB): 128 rows x 256 cols

  const int tid = threadIdx.x;
  const int m0 = blockIdx.x * 128;
  const int w = tid >> 6, lane = tid & 63, l16 = lane & 15, kg = lane >> 4;
  const int wr = w >> 2, wc = w & 3;

  constexpr int NC1 = IS_EDGE ? 12 : 8;

  // gather role: thread stages row (tid>>2), 8 cols at (tid&3)*8 within 32-col chunk
  const int grow = tid >> 2;
  const int gk = tid & 3;
  const int grc = min(m0 + grow, M - 1);
  const int aslot = (grow >> 4) * 64 + gk * 16 + (grow & 15);
  int gsr = 0, gdr = 0;
  if (IS_EDGE) { gsr = src[grc]; gdr = dst[grc]; }

  // bias / LN param preload
  float b1v[4], b2v[4];
#pragma unroll
  for (int ct = 0; ct < 4; ++ct) {
    int col = wc * 64 + ct * 16 + l16;
    b1v[ct] = b1[col];
    b2v[ct] = b2[col];
  }
  float b3v[8], gv[8], bev[8];
#pragma unroll
  for (int f = 0; f < 8; ++f) {
    int col = f * 16 + l16;
    b3v[f] = b3[col]; gv[f] = gam[col]; bev[f] = bet[col];
  }

  f32x4 acc[16];
#pragma unroll
  for (int i = 0; i < 16; ++i) { f32x4 z = {0.f, 0.f, 0.f, 0.f}; acc[i] = z; }

  auto bsbuf = [&](int v) -> short* { return BsBase + (size_t)(v % 3) * 8192; };
  auto stage1024 = [&](int v) {
    const short* g = wAll + (size_t)v * 8192;
    short* l = bsbuf(v);
    gld_lds16(g + (size_t)tid * 8, l + (size_t)tid * 8);
    gld_lds16(g + (size_t)(512 + tid) * 8, l + (size_t)(512 + tid) * 8);
  };

  auto gatherA = [&](int c) -> F8 {
    const float* q;
    if (IS_EDGE) {
      if (c < 4)      q = node_emb + (size_t)gsr * 128 + c * 32 + gk * 8;
      else if (c < 8) q = node_emb + (size_t)gdr * 128 + (c - 4) * 32 + gk * 8;
      else            q = edge_emb + (size_t)grc * 128 + (c - 8) * 32 + gk * 8;
    } else {
      if (c < 4) q = node_emb + (size_t)grc * 128 + c * 32 + gk * 8;
      else       q = agg + (size_t)grc * 128 + (c - 4) * 32 + gk * 8;
    }
    F8 r;
    r.a = *(const float4*)q;
    r.b = *(const float4*)(q + 4);
    return r;
  };
  auto writeA = [&](const F8& p, int buf) {
    float t[8];
    *(float4*)t = p.a; *(float4*)(t + 4) = p.b;
    bf16x8 o;
#pragma unroll
    for (int e = 0; e < 8; ++e) o[e] = f2bf(t[e]);
    *(bf16x8*)&AsBase[(size_t)buf * 4096 + (size_t)aslot * 8] = o;
  };

  auto mfma16 = [&](bf16x8* a, bf16x8* b) {
#pragma unroll
    for (int rt = 0; rt < 4; ++rt)
#pragma unroll
      for (int ct = 0; ct < 4; ++ct)
        acc[rt * 4 + ct] = __builtin_amdgcn_mfma_f32_16x16x32_bf16(a[rt], b[ct], acc[rt * 4 + ct], 0, 0, 0);
  };

  auto compA = [&](int i) {
    const short* Ap = AsBase + (size_t)(i & 1) * 4096;
    const short* Bp = bsbuf(i);
    bf16x8 a[4], b[4];
#pragma unroll
    for (int rt = 0; rt < 4; ++rt)
      a[rt] = *(const bf16x8*)&Ap[(size_t)((wr * 4 + rt) * 64 + kg * 16 + l16) * 8];
#pragma unroll
    for (int ct = 0; ct < 4; ++ct)
      b[ct] = *(const bf16x8*)&Bp[(size_t)((wc * 4 + ct) * 64 + lane) * 8];
    mfma16(a, b);
  };

  auto computeH = [&](int j, const short* Bp) {
    bf16x8 a[4], b[4];
#pragma unroll
    for (int rt = 0; rt < 4; ++rt) {
      int row = wr * 64 + rt * 16 + l16;
      int ch = (j * 32 + kg * 8) ^ ((row & 7) << 3);
      a[rt] = *(const bf16x8*)&Hs[(size_t)row * 256 + ch];
    }
#pragma unroll
    for (int ct = 0; ct < 4; ++ct)
      b[ct] = *(const bf16x8*)&Bp[(size_t)((wc * 4 + ct) * 64 + lane) * 8];
    mfma16(a, b);
  };

  auto writeH = [&](const float* bv) {
#pragma unroll
    for (int rt = 0; rt < 4; ++rt)
#pragma unroll
      for (int q = 0; q < 4; ++q) {
        int row = wr * 64 + rt * 16 + kg * 4 + q;
        s16x4 v;
#pragma unroll
        for (int ct = 0; ct < 4; ++ct)
          v[ct] = f2bf(fmaxf(acc[rt * 4 + ct][q] + bv[ct], 0.f));
        int ch = (wc * 64 + l16 * 4) ^ ((row & 7) << 3);
        *(s16x4*)&Hs[(size_t)row * 256 + ch] = v;
      }
#pragma unroll
    for (int i = 0; i < 16; ++i) { f32x4 z = {0.f, 0.f, 0.f, 0.f}; acc[i] = z; }
  };

  auto computeL3 = [&](int kk, const short* Bp) {  // kk = 32-chunk index 0..7
    int row = w * 16 + l16;
    int ch = (kk * 32 + kg * 8) ^ ((row & 7) << 3);
    bf16x8 a = *(const bf16x8*)&Hs[(size_t)row * 256 + ch];
    const short* Bsub = Bp + (size_t)(kk & 1) * 4096;
#pragma unroll
    for (int f = 0; f < 8; ++f) {
      bf16x8 b = *(const bf16x8*)&Bsub[(size_t)(f * 64 + lane) * 8];
      acc[f] = __builtin_amdgcn_mfma_f32_16x16x32_bf16(a, b, acc[f], 0, 0, 0);
    }
  };

  // ---- layer 1 (K = NC1*32, N = 256), depth-2 staged pipeline ----
  F8 hold0 = gatherA(0);
  stage1024(0);
  stage1024(1);
  F8 hold = gatherA(1);
  writeA(hold0, 0);
  BARX(4);

#pragma unroll
  for (int i = 0; i < NC1; ++i) {
    stage1024(i + 2);  // L1 chunks then W2 chunks, contiguous in wAll
    F8 gnew = hold;
    if (i + 2 < NC1) gnew = gatherA(i + 2);
    compA(i);
    if (i + 1 < NC1) writeA(hold, (i + 1) & 1);
    if (i + 2 < NC1) { BARX(4); } else { BARX(2); }
    hold = gnew;
  }
  writeH(b1v);
  BARLG();

  // ---- layer 2 (K = 256, N = 256) ----
#pragma unroll
  for (int j = 0; j < 8; ++j) {
    int p = NC1 + j;
    stage1024(p + 2);
    computeH(j, bsbuf(p));
    BARX(2);
  }
  writeH(b2v);
  BARLG();

  // ---- layer 3 (K = 256, N = 128), row-split, 2 sub-chunks per staged unit ----
#pragma unroll
  for (int k = 0; k < 4; ++k) {
    int p = NC1 + 8 + k;
    if (k < 2) stage1024(p + 2);
    computeL3(2 * k, bsbuf(p));
    computeL3(2 * k + 1, bsbuf(p));
    if (k == 0 || k == 1) { BARX(2); }
    else if (k == 2)      { BARX(0); }
  }

  // ---- epilogue: bias + LayerNorm + residual ----
#pragma unroll
  for (int q = 0; q < 4; ++q) {
    int rg = m0 + w * 16 + kg * 4 + q;
    float o[8], s1 = 0.f, s2 = 0.f;
#pragma unroll
    for (int f = 0; f < 8; ++f) {
      float x = acc[f][q] + b3v[f];
      o[f] = x; s1 += x; s2 += x * x;
    }
#pragma unroll
    for (int m = 1; m <= 8; m <<= 1) { s1 += __shfl_xor(s1, m); s2 += __shfl_xor(s2, m); }
    float mu = s1 * (1.f / 128.f);
    float var = s2 * (1.f / 128.f) - mu * mu;
    float rs = rsqrtf(var + 1e-5f);
    if (rg < M) {
      const float* resid = (IS_EDGE ? edge_emb : node_emb) + (size_t)rg * 128;
      float* op = out_base + (size_t)rg * 128;
#pragma unroll
      for (int f = 0; f < 8; ++f) {
        int col = f * 16 + l16;
        op[col] = (o[f] - mu) * rs * gv[f] + bev[f] + resid[col];
      }
    }
  }
}

extern "C" void kernel_launch(void* const* d_in, const int* in_sizes, int n_in,
                              void* d_out, int out_size, void* d_ws, size_t ws_size,
                              hipStream_t stream) {
  const float* node_emb = (const float*)d_in[0];
  const float* edge_emb = (const float*)d_in[1];
  const int*   src      = (const int*)d_in[2];
  const int*   dst      = (const int*)d_in[3];
  const float* eW1 = (const float*)d_in[5];
  const float* eb1 = (const float*)d_in[6];
  const float* eW2 = (const float*)d_in[7];
  const float* eb2 = (const float*)d_in[8];
  const float* eW3 = (const float*)d_in[9];
  const float* eb3 = (const float*)d_in[10];
  const float* eg  = (const float*)d_in[11];
  const float* ebt = (const float*)d_in[12];
  const float* nW1 = (const float*)d_in[13];
  const float* nb1 = (const float*)d_in[14];
  const float* nW2 = (const float*)d_in[15];
  const float* nb2 = (const float*)d_in[16];
  const float* nW3 = (const float*)d_in[17];
  const float* nb3 = (const float*)d_in[18];
  const float* ng  = (const float*)d_in[19];
  const float* nbt = (const float*)d_in[20];

  const int Nn = in_sizes[0] / 128;
  const int Ee = in_sizes[2];

  char* ws = (char*)d_ws;
  float* agg  = (float*)ws;  ws += (size_t)Nn * 128 * 4;
  int* cnt_i  = (int*)ws;    ws += (size_t)Nn * 4;
  int* cursor = (int*)ws;    ws += (size_t)Nn * 4;
  int* offv   = (int*)ws;    ws += (size_t)(Nn + 1) * 4;
  int* eidx   = (int*)ws;    ws += (size_t)Ee * 4;
  ws = (char*)(((uintptr_t)ws + 15) & ~(uintptr_t)15);
  short* wp = (short*)ws;
  // edge weights contiguous: W1 (12x8192) | W2 (8x8192) | W3 (8x4096)
  short* eAll = wp;                 // 196608 shorts total
  short* nAll = wp + 196608;        // node: W1 (8x8192) | W2 (8x8192) | W3 (8x4096)

  float* out_node = (float*)d_out;
  float* out_edge = out_node + (size_t)Nn * 128;

  hipMemsetAsync(cnt_i, 0, (size_t)Nn * 4, stream);

  prep_kernel<false><<<48, 256, 0, stream>>>(eW1, eAll, 384, 256);
  prep_kernel<true><<<32, 256, 0, stream>>>(eW2, eAll + 98304, 256, 256);
  prep_kernel<true><<<16, 256, 0, stream>>>(eW3, eAll + 163840, 256, 128);
  prep_kernel<false><<<32, 256, 0, stream>>>(nW1, nAll, 256, 256);
  prep_kernel<true><<<32, 256, 0, stream>>>(nW2, nAll + 65536, 256, 256);
  prep_kernel<true><<<16, 256, 0, stream>>>(nW3, nAll + 131072, 256, 128);

  count_kernel<<<(Ee + 255) / 256, 256, 0, stream>>>(dst, cnt_i, Ee);
  scan_kernel<<<1, 1024, 0, stream>>>(cnt_i, offv, cursor, Nn);
  scatter_kernel<<<(Ee + 255) / 256, 256, 0, stream>>>(dst, cursor, eidx, Ee);

  mlp_kernel<true><<<(Ee + 127) / 128, 512, 131072, stream>>>(
      node_emb, edge_emb, src, dst, eAll,
      eb1, eb2, eb3, eg, ebt, agg, out_edge, Ee);

  agg_kernel<<<(Nn + 3) / 4, 256, 0, stream>>>(out_edge, eidx, offv, agg, Nn);

  mlp_kernel<false><<<(Nn + 127) / 128, 512, 131072, stream>>>(
      node_emb, edge_emb, src, dst, nAll,
      nb1, nb2, nb3, ng, nbt, agg, out_node, Nn);
}